// Round 5
// baseline (292.050 us; speedup 1.0000x reference)
//
#include <hip/hip_runtime.h>

typedef unsigned int u32;
typedef unsigned short u16;
typedef __attribute__((ext_vector_type(8))) short bf16x8;    // 8 bf16 = 4 VGPRs
typedef __attribute__((ext_vector_type(4))) float f32x4;
typedef __attribute__((ext_vector_type(16))) float f32x16;   // 32x32 MFMA accumulator

#define KN 8192
#define DD 256
#define HW 1024
#define NP 32768
#define SPLITS 2
#define KSPLIT 4096
#define PXT 128
#define NTT 128

__device__ __forceinline__ u16 rne_bf16(float x) {
    u32 u = __float_as_uint(x);
    return (u16)((u + 0x7FFF + ((u >> 16) & 1)) >> 16);
}

__device__ __forceinline__ void glds16(const void* g, void* ldsbase) {
    __builtin_amdgcn_global_load_lds((const __attribute__((address_space(1))) u32*)g,
                                     (__attribute__((address_space(3))) u32*)ldsbase, 16, 0, 0);
}

// ---------------- merged prep: enorm | eT/eTf transpose | A build (unchanged, proven) ----------------
__global__ void prep_kernel(const float* __restrict__ e, const float* __restrict__ z,
                            u16* __restrict__ eT, float* __restrict__ eTf,
                            float* __restrict__ e2f, u16* __restrict__ A) {
    const int t = threadIdx.x;
    const int bid = blockIdx.x;
    if (bid < 32) {
        int k = bid * 256 + t;
        float acc = 0.f;
#pragma unroll 8
        for (int d = 0; d < DD; ++d) {
            float v = e[(size_t)d * KN + k];
            acc = fmaf(v, v, acc);
        }
        e2f[k] = acc;
    } else if (bid < 544) {
        __shared__ float tt[64][65];
        const int b2 = bid - 32;
        const int kt = b2 & 127;     // 0..127
        const int dt = b2 >> 7;      // 0..3
        const float* ep = e + (size_t)(dt * 64) * KN + kt * 64;
        {
            int k = t & 63, d0 = t >> 6;
#pragma unroll
            for (int j = 0; j < 16; ++j) tt[d0 + j * 4][k] = ep[(size_t)(d0 + j * 4) * KN + k];
        }
        __syncthreads();
        int k = t >> 2, c0 = (t & 3) * 16;
        u16 hi[16];
        float fv[16];
#pragma unroll
        for (int j = 0; j < 16; ++j) {
            float v = tt[c0 + j][k];
            fv[j] = v;
            hi[j] = rne_bf16(v);
        }
        u16* rowp = eT + (size_t)(kt * 64 + k) * 256 + dt * 64 + c0;
        *(uint4*)(rowp) = *(uint4*)(hi);
        *(uint4*)(rowp + 8) = *(uint4*)(hi + 8);
        float* rowpf = eTf + (size_t)(kt * 64 + k) * 256 + dt * 64 + c0;
#pragma unroll
        for (int j = 0; j < 4; ++j) *(float4*)(rowpf + j * 4) = *(float4*)(fv + j * 4);
    } else {
        __shared__ float tt[64][65];
        const int b3 = bid - 544;
        const int pt = b3 & 15;          // 0..15
        const int dt = (b3 >> 4) & 3;    // 0..3
        const int b  = b3 >> 6;          // 0..31
        const float* zp = z + (size_t)b * (DD * HW) + (size_t)(dt * 64) * HW + pt * 64;
        {
            int p = t & 63, d0 = t >> 6;
#pragma unroll
            for (int j = 0; j < 16; ++j) tt[d0 + j * 4][p] = zp[(size_t)(d0 + j * 4) * HW + p];
        }
        __syncthreads();
        int p = t >> 2, c0 = (t & 3) * 16;
        int n = b * HW + pt * 64 + p;
        u16 hi[16];
#pragma unroll
        for (int j = 0; j < 16; ++j) hi[j] = rne_bf16(tt[c0 + j][p]);
        u16* rowp = A + (size_t)n * 256 + dt * 64 + c0;
        *(uint4*)(rowp) = *(uint4*)(hi);
        *(uint4*)(rowp + 8) = *(uint4*)(hi + 8);
    }
}

// ---------------- main: R7-proven schedule, 32x32x16 MFMA (R5) ----------------
// R5 theory: R4 proved the limiter at the R7 structure is NOT LDS bytes (cutting them 20%
// was -4%); it is the fixed per-kit serialization at ~41-46% structural efficiency. So lower
// BOTH pipe floors by switching the MFMA shape: 32x32x16 moves 2x FLOP per b128 operand read
// (floor 66->57.5us MFMA, 102->77us LDS) while keeping the R7 schedule, staging, LDS layout,
// XOR swizzle, and 2 blocks/CU EXACTLY as measured at 143.6us/41%.
// Fragment mappings (HW-verified per guide m74/m101):
//   A: row = l&31, k_off = (l>>5)*8 ; B: col = l&31, k_off = (l>>5)*8
//   C: col = l&31, row = (reg&3) + 8*(reg>>2) + 4*(l>>5), reg in [0,16)
// Bank check (b128 reads): lanes 0-31 rows base..+31, chunk s2^(l&7); 8 rows cover all 8
// 16B-slots; 8 words/bank uniform -> conflict-free (same property as the measured-0 R7 reads).
// Wave grid 2x2 (wave tile 64x64 = 2x2 MFMA tiles): acc[2][2] f32x16 = 64 regs.
// Per kit per wave: 16 ds_read_b128 + 16 MFMA (was 20 reads + 32 MFMA at 16x16).
// Top-3 contract: per-lane cols = 2/nt -> per-nt top-2 fold is lossless; across 32 nts each
// lane owns 64 cols (vs 256 in R7) -> colocation risk strictly lower than the proven scheme.

__launch_bounds__(256, 2)
__global__ void argmin_mfma_kernel(const u16* __restrict__ A,   // [32768][256]
                                   const u16* __restrict__ eT,  // [8192][256]
                                   const float* __restrict__ e2f,
                                   int* __restrict__ keys) {    // [3][2][NP]
    __shared__ u16 Ast[4][PXT * 64];  // 64 KB resident A, XOR-swizzled slots
    __shared__ u16 Bst[NTT * 64];     // 16 KB streamed B

    const int t = threadIdx.x;
    const int w = t >> 6;        // wave 0..3
    const int l = t & 63;
    const int wm = w & 1;        // M-group: rows wm*64 .. +64
    const int wn = w >> 1;       // N-group: cols wn*64 .. +64
    const int split = blockIdx.x & 1;
    const int pxt   = blockIdx.x >> 1;
    const int px0 = pxt * PXT;
    const int kb0 = split * KSPLIT;

    const int swz  = (l & 7) ^ ((l >> 3) & 7);
    const int srow = l >> 3;
    const int c32  = l & 31;     // A-row / B-col / C-col lane index
    const int h    = l >> 5;     // k-half selector & C-row offset
    const int slx  = l & 7;      // (row&7) for fragment reads (row = base32 + c32, base32%8==0)

    // ---- A prologue stage (identical to R7): rows w*32..+32, 4 kits ----
#pragma unroll
    for (int c = 0; c < 4; ++c)
#pragma unroll
        for (int i = 0; i < 4; ++i) {
            int r0 = w * 32 + i * 8;
            const u16* gp = A + (size_t)(px0 + r0 + srow) * 256 + c * 64 + swz * 8;
            glds16(gp, &Ast[c][r0 * 64]);
        }

    int b1[32], b2[32];
#pragma unroll
    for (int i = 0; i < 32; ++i) { b1[i] = 0x7FFFFFFF; b2[i] = 0x7FFFFFFF; }

    for (int nt = 0; nt < KSPLIT / NTT; ++nt) {
        const int n0 = kb0 + nt * NTT;
        f32x16 acc[2][2];
#pragma unroll
        for (int ti = 0; ti < 2; ++ti)
#pragma unroll
            for (int tj = 0; tj < 2; ++tj)
#pragma unroll
                for (int r = 0; r < 16; ++r) acc[ti][tj][r] = 0.f;

        for (int kit = 0; kit < 4; ++kit) {
            __syncthreads();
#pragma unroll
            for (int i = 0; i < 4; ++i) {
                int r0 = w * 32 + i * 8;
                const u16* gp = eT + (size_t)(n0 + r0 + srow) * 256 + kit * 64 + swz * 8;
                glds16(gp, &Bst[r0 * 64]);
            }
            __syncthreads();
#pragma unroll
            for (int sl = 0; sl < 4; ++sl) {         // k-slice of 16 within the kit's 64
                const int chunk = sl * 2 + h;        // logical 8-elem k-chunk 0..7
                const int slt = (chunk ^ slx) * 8;
                bf16x8 af[2], bfr[2];
#pragma unroll
                for (int ti = 0; ti < 2; ++ti) {
                    int row = wm * 64 + ti * 32 + c32;
                    af[ti] = *(const bf16x8*)&Ast[kit][row * 64 + slt];
                }
#pragma unroll
                for (int tj = 0; tj < 2; ++tj) {
                    int row = wn * 64 + tj * 32 + c32;
                    bfr[tj] = *(const bf16x8*)&Bst[row * 64 + slt];
                }
#pragma unroll
                for (int ti = 0; ti < 2; ++ti)
#pragma unroll
                    for (int tj = 0; tj < 2; ++tj)
                        acc[ti][tj] = __builtin_amdgcn_mfma_f32_32x32x16_bf16(
                            af[ti], bfr[tj], acc[ti][tj], 0, 0, 0);
            }
        }

        // fold this nt's distances into per-row running top-2 keys
        float e2c[2];
        int   kcc[2];
#pragma unroll
        for (int tj = 0; tj < 2; ++tj) {
            kcc[tj] = n0 + wn * 64 + tj * 32 + c32;
            e2c[tj] = e2f[kcc[tj]] * 256.f;
        }
#pragma unroll
        for (int ti = 0; ti < 2; ++ti)
#pragma unroll
            for (int reg = 0; reg < 16; ++reg) {
                float d0 = fmaf(acc[ti][0][reg], -512.f, e2c[0]);
                float d1 = fmaf(acc[ti][1][reg], -512.f, e2c[1]);
                int ky0 = (int)d0 * 8192 + kcc[0];
                int ky1 = (int)d1 * 8192 + kcc[1];
                int kmin = min(ky0, ky1);
                int s = ti * 16 + reg;
                int v1 = min(b1[s], kmin);
                int x  = max(b1[s], kmin);
                b2[s] = min(b2[s], x);
                b1[s] = v1;
            }
    }

    // ---- per-slot 32-lane top-3 tree, then cross-wn merge via LDS (R4-proven tail) ----
    __syncthreads();               // all waves done reading Bst before overlay
    int* mrg = (int*)&Bst[0];      // 2*128*3 ints = 3 KB, Bst is dead now
#pragma unroll
    for (int s = 0; s < 32; ++s) {
        int c1 = b1[s], c2 = b2[s], c3 = 0x7FFFFFFF;
#pragma unroll
        for (int m = 1; m < 32; m <<= 1) {           // reduce within 32-lane halves
            int a1 = __shfl_xor(c1, m, 64);
            int a2 = __shfl_xor(c2, m, 64);
            int a3 = __shfl_xor(c3, m, 64);
            int m1 = min(c1, a1);
            int xx = max(c1, a1);
            int mn2 = min(c2, a2);
            int m2 = min(xx, mn2);
            int m3 = min(min(max(c2, a2), max(xx, mn2)), min(c3, a3));
            c1 = m1; c2 = m2; c3 = m3;
        }
        if (c32 == 0) {                               // lanes 0 and 32 (different rows)
            int ti = s >> 4, reg = s & 15;
            int row = wm * 64 + ti * 32 + (reg & 3) + 8 * (reg >> 2) + 4 * h;
            int o = (wn * 128 + row) * 3;
            mrg[o] = c1; mrg[o + 1] = c2; mrg[o + 2] = c3;
        }
    }
    __syncthreads();
    if (t < 128) {
        int a1 = mrg[t * 3], a2 = mrg[t * 3 + 1], a3 = mrg[t * 3 + 2];
        int u1 = mrg[(128 + t) * 3], u2 = mrg[(128 + t) * 3 + 1], u3 = mrg[(128 + t) * 3 + 2];
        int x1 = min(a1, u1), y1 = max(a1, u1);
        int n2 = min(a2, u2), M2 = max(a2, u2);
        int c1 = x1;
        int c2 = min(y1, n2);
        int c3 = min(max(y1, n2), min(M2, min(a3, u3)));
        int row = px0 + t;
        keys[split * NP + row]       = c1;
        keys[(2 + split) * NP + row] = c2;
        keys[(4 + split) * NP + row] = c3;
    }
}

// -------- finalize (fast-ws): dots + select + gather + out + loss, one pass (unchanged) --------
__global__ void finalize_kernel(const int* __restrict__ keys,
                                const float* __restrict__ z,
                                const float* __restrict__ eTf,
                                const float* __restrict__ e2f,
                                float* __restrict__ out,
                                float* __restrict__ loss) {
    __shared__ float smem[DD * 65];   // phase 1: zt[d*65+p]; phase 2: qt[p*257+d]
    __shared__ int   kc[384];
    __shared__ float dval[384];
    __shared__ int   kidx[64];
    const int t = threadIdx.x;
    const int n0 = blockIdx.x * 64;
    const float* zp = z + (size_t)(n0 >> 10) * (DD * HW) + (n0 & (HW - 1));

    for (int i = t; i < DD * 64; i += 256) {
        int d = i >> 6, p = i & 63;
        smem[d * 65 + p] = zp[(size_t)d * HW + p];   // coalesced
    }
    for (int i = t; i < 384; i += 256)
        kc[i] = keys[(i % 6) * NP + n0 + i / 6] & 8191;
    __syncthreads();

    const int l = t & 63, w = t >> 6;
    const int j = l & 15;   // lane within 16-lane dot group
    const int s = l >> 4;   // dot-group id within wave
#pragma unroll 2
    for (int it = 0; it < 24; ++it) {
        int dot = it * 16 + w * 4 + s;      // 0..383
        int p = dot / 6;
        int k = kc[dot];
        const float* er = eTf + (size_t)k * 256;
        float a = 0.f;
#pragma unroll
        for (int cc = 0; cc < 16; ++cc)
            a = fmaf(smem[(cc * 16 + j) * 65 + p], er[cc * 16 + j], a);
        a += __shfl_xor(a, 1, 64);
        a += __shfl_xor(a, 2, 64);
        a += __shfl_xor(a, 4, 64);
        a += __shfl_xor(a, 8, 64);
        if (j == 0) dval[dot] = fmaf(-2.f, a, e2f[k]);
    }
    __syncthreads();
    if (t < 64) {
        float bv = dval[t * 6];
        int   bk = kc[t * 6];
#pragma unroll
        for (int c = 1; c < 6; ++c) {
            float dv = dval[t * 6 + c];
            int   kk = kc[t * 6 + c];
            if (dv < bv || (dv == bv && kk < bk)) { bv = dv; bk = kk; }
        }
        kidx[t] = bk;
    }
    __syncthreads();

    // phase 2: bounce the 64 winning eTf rows through smem (zt is dead)
    float* qt = smem;                 // [p][d] pad 257 (257%32==1: conflict-free)
    for (int m = 0; m < 64; ++m)      // row m: 256 threads read the 1 KB row
        qt[m * 257 + t] = eTf[(size_t)kidx[m] * 256 + t];
    __syncthreads();

    const int p = t & 63, q = t >> 6;
    const size_t base = (size_t)(n0 >> 10) * (DD * HW) + (n0 & (HW - 1)) + p;
    float acc = 0.f;
#pragma unroll 8
    for (int i = 0; i < 64; ++i) {
        int d = q * 64 + i;
        float ev = qt[p * 257 + d];
        float zv = z[base + (size_t)d * HW];   // coalesced, L2-hot re-read
        out[base + (size_t)d * HW] = zv + (ev - zv);
        float df = ev - zv;
        acc = fmaf(df, df, acc);
    }
#pragma unroll
    for (int off = 32; off > 0; off >>= 1) acc += __shfl_down(acc, off, 64);
    __shared__ float part[4];
    if ((t & 63) == 0) part[t >> 6] = acc;
    __syncthreads();
    if (t == 0) {
        float s2 = (part[0] + part[1] + part[2] + part[3]) * (1.25f / 8388608.f);
        atomicAdd(loss, s2);
    }
}

// -------- slow-ws path: proven separate combine + gather (unchanged) --------
__global__ void combine_kernel(const int* __restrict__ keys,
                               const float* __restrict__ z,
                               const float* __restrict__ eTf,
                               const float* __restrict__ e2f,
                               int* __restrict__ idx) {
    __shared__ float zt[DD * 65];
    __shared__ int   kc[384];
    __shared__ float dval[384];
    const int t = threadIdx.x;
    const int n0 = blockIdx.x * 64;
    const float* zp = z + (size_t)(n0 >> 10) * (DD * HW) + (n0 & (HW - 1));
    for (int i = t; i < DD * 64; i += 256) {
        int d = i >> 6, p = i & 63;
        zt[d * 65 + p] = zp[(size_t)d * HW + p];
    }
    for (int i = t; i < 384; i += 256)
        kc[i] = keys[(i % 6) * NP + n0 + i / 6] & 8191;
    __syncthreads();

    const int l = t & 63, w = t >> 6;
    const int j = l & 15;
    const int s = l >> 4;
#pragma unroll 2
    for (int it = 0; it < 24; ++it) {
        int dot = it * 16 + w * 4 + s;
        int p = dot / 6;
        int k = kc[dot];
        const float* er = eTf + (size_t)k * 256;
        float a = 0.f;
#pragma unroll
        for (int cc = 0; cc < 16; ++cc)
            a = fmaf(zt[(cc * 16 + j) * 65 + p], er[cc * 16 + j], a);
        a += __shfl_xor(a, 1, 64);
        a += __shfl_xor(a, 2, 64);
        a += __shfl_xor(a, 4, 64);
        a += __shfl_xor(a, 8, 64);
        if (j == 0) dval[dot] = fmaf(-2.f, a, e2f[k]);
    }
    __syncthreads();
    if (t < 64) {
        float bv = dval[t * 6];
        int   bk = kc[t * 6];
#pragma unroll
        for (int c = 1; c < 6; ++c) {
            float dv = dval[t * 6 + c];
            int   kk = kc[t * 6 + c];
            if (dv < bv || (dv == bv && kk < bk)) { bv = dv; bk = kk; }
        }
        idx[n0 + t] = bk;
    }
}

__global__ void gather_slow_kernel(const float* __restrict__ z,
                                   const float* __restrict__ e,
                                   const int* __restrict__ idx,
                                   float* __restrict__ out,
                                   float* __restrict__ loss) {
    const int t = threadIdx.x;
    const int n0 = blockIdx.x * 64;
    __shared__ int kidx[64];
    if (t < 64) kidx[t] = idx[n0 + t];
    __syncthreads();

    const int p = t & 63;
    const int d0 = t >> 6;
    const size_t base = (size_t)(n0 >> 10) * (DD * HW) + (n0 & (HW - 1)) + p;
    const int kk = kidx[p];

    float acc = 0.f;
    for (int d = d0; d < DD; d += 4) {
        float ev = e[(size_t)d * KN + kk];
        float zv = z[base + (size_t)d * HW];
        out[base + (size_t)d * HW] = zv + (ev - zv);
        float df = ev - zv;
        acc = fmaf(df, df, acc);
    }
#pragma unroll
    for (int off = 32; off > 0; off >>= 1) acc += __shfl_down(acc, off, 64);
    __shared__ float part[4];
    if ((t & 63) == 0) part[t >> 6] = acc;
    __syncthreads();
    if (t == 0) {
        float s = (part[0] + part[1] + part[2] + part[3]) * (1.25f / 8388608.f);
        atomicAdd(loss, s);
    }
}

extern "C" void kernel_launch(void* const* d_in, const int* in_sizes, int n_in,
                              void* d_out, int out_size, void* d_ws, size_t ws_size,
                              hipStream_t stream) {
    const float* z = (const float*)d_in[0];   // [32,256,32,32] fp32
    const float* e = (const float*)d_in[1];   // [256,8192] fp32
    float* out = (float*)d_out;
    float* loss = out + (size_t)NP * DD;      // element 8388608

    char* ob = (char*)d_out;
    char* ws = (char*)d_ws;
    u16* Acat = (u16*)ob;                            // [0, 16Mi) — consumed by argmin
    u16* eT   = (u16*)(ob + ((size_t)16 << 20));     // [16Mi, 20Mi) — consumed by argmin

    float* e2f = (float*)ws;                         // 32 KB (proven-safe region)
    int*   idx = (int*)(ws + (32 << 10));            // 128 KB
    int*   keys;
    float* eTf;
    const bool fastws = ws_size >= ((size_t)10 << 20);
    if (fastws) {
        keys = (int*)(ws + (160 << 10));             // 768 KB @ 160K
        eTf  = (float*)(ws + ((size_t)1 << 20));     // 8 MB @ 1M
    } else {
        keys = (int*)(ob + ((size_t)20 << 20));      // d_out scratch (R6-proven)
        eTf  = (float*)(ob + ((size_t)23 << 20));
    }

    prep_kernel<<<2592, 256, 0, stream>>>(e, z, eT, eTf, e2f, Acat);
    argmin_mfma_kernel<<<SPLITS * (NP / PXT), 256, 0, stream>>>(Acat, eT, e2f, keys);
    hipMemsetAsync(loss, 0, sizeof(float), stream);
    if (fastws) {
        finalize_kernel<<<NP / 64, 256, 0, stream>>>(keys, z, eTf, e2f, out, loss);
    } else {
        combine_kernel<<<NP / 64, 256, 0, stream>>>(keys, z, eTf, e2f, idx);
        gather_slow_kernel<<<NP / 64, 256, 0, stream>>>(z, e, idx, out, loss);
    }
}

// Round 6
// 288.451 us; speedup vs baseline: 1.0125x; 1.0125x over previous
//
#include <hip/hip_runtime.h>

typedef unsigned int u32;
typedef unsigned short u16;
typedef __attribute__((ext_vector_type(8))) short bf16x8;    // 8 bf16 = 4 VGPRs
typedef __attribute__((ext_vector_type(4))) float f32x4;
typedef __attribute__((ext_vector_type(16))) float f32x16;   // 32x32 MFMA accumulator

#define KN 8192
#define DD 256
#define HW 1024
#define NP 32768
#define SPLITS 2
#define KSPLIT 4096
#define PXT 128
#define NTT 128

__device__ __forceinline__ u16 rne_bf16(float x) {
    u32 u = __float_as_uint(x);
    return (u16)((u + 0x7FFF + ((u >> 16) & 1)) >> 16);
}

__device__ __forceinline__ void glds16(const void* g, void* ldsbase) {
    __builtin_amdgcn_global_load_lds((const __attribute__((address_space(1))) u32*)g,
                                     (__attribute__((address_space(3))) u32*)ldsbase, 16, 0, 0);
}

// ---------------- merged prep: enorm | eT/eTf transpose | A build (unchanged, proven) ----------------
__global__ void prep_kernel(const float* __restrict__ e, const float* __restrict__ z,
                            u16* __restrict__ eT, float* __restrict__ eTf,
                            float* __restrict__ e2f, u16* __restrict__ A) {
    const int t = threadIdx.x;
    const int bid = blockIdx.x;
    if (bid < 32) {
        int k = bid * 256 + t;
        float acc = 0.f;
#pragma unroll 8
        for (int d = 0; d < DD; ++d) {
            float v = e[(size_t)d * KN + k];
            acc = fmaf(v, v, acc);
        }
        e2f[k] = acc;
    } else if (bid < 544) {
        __shared__ float tt[64][65];
        const int b2 = bid - 32;
        const int kt = b2 & 127;     // 0..127
        const int dt = b2 >> 7;      // 0..3
        const float* ep = e + (size_t)(dt * 64) * KN + kt * 64;
        {
            int k = t & 63, d0 = t >> 6;
#pragma unroll
            for (int j = 0; j < 16; ++j) tt[d0 + j * 4][k] = ep[(size_t)(d0 + j * 4) * KN + k];
        }
        __syncthreads();
        int k = t >> 2, c0 = (t & 3) * 16;
        u16 hi[16];
        float fv[16];
#pragma unroll
        for (int j = 0; j < 16; ++j) {
            float v = tt[c0 + j][k];
            fv[j] = v;
            hi[j] = rne_bf16(v);
        }
        u16* rowp = eT + (size_t)(kt * 64 + k) * 256 + dt * 64 + c0;
        *(uint4*)(rowp) = *(uint4*)(hi);
        *(uint4*)(rowp + 8) = *(uint4*)(hi + 8);
        float* rowpf = eTf + (size_t)(kt * 64 + k) * 256 + dt * 64 + c0;
#pragma unroll
        for (int j = 0; j < 4; ++j) *(float4*)(rowpf + j * 4) = *(float4*)(fv + j * 4);
    } else {
        __shared__ float tt[64][65];
        const int b3 = bid - 544;
        const int pt = b3 & 15;          // 0..15
        const int dt = (b3 >> 4) & 3;    // 0..3
        const int b  = b3 >> 6;          // 0..31
        const float* zp = z + (size_t)b * (DD * HW) + (size_t)(dt * 64) * HW + pt * 64;
        {
            int p = t & 63, d0 = t >> 6;
#pragma unroll
            for (int j = 0; j < 16; ++j) tt[d0 + j * 4][p] = zp[(size_t)(d0 + j * 4) * HW + p];
        }
        __syncthreads();
        int p = t >> 2, c0 = (t & 3) * 16;
        int n = b * HW + pt * 64 + p;
        u16 hi[16];
#pragma unroll
        for (int j = 0; j < 16; ++j) hi[j] = rne_bf16(tt[c0 + j][p]);
        u16* rowp = A + (size_t)n * 256 + dt * 64 + c0;
        *(uint4*)(rowp) = *(uint4*)(hi);
        *(uint4*)(rowp + 8) = *(uint4*)(hi + 8);
    }
}

// ---------------- main: R7 schedule, 32x32x16 MFMA, stride-16-quad-safe swizzle (R6) ----------------
// R5 post-mortem: 1.678e7 bank conflicts = 4 extra cyc on EVERY fragment read. Fingerprint
// analysis vs the measured-0 R7 pattern shows the LDS conflict unit resolves wave64 b128 in
// STRIDE-16 LANE QUADS {l,l+16,l+32,l+48}: R7's slot fn gave 4 distinct slots per quad, R5's
// (chunk = l>>5) only 2. The 32x32 fragment layout forces chunk=(l>>5), so fix the SWIZZLE:
//   phys_slot(row, chunk) = chunk ^ (row&7) ^ (((row>>4)&1)<<2)
// Fragment reads: (row>>4)&1 == (l>>4)&1 -> quad slots {+0,+1,+4,+5}: 4 distinct (free);
// stride-8 pairs stay 2-way (free, same signature as R7's 0-conflict pattern).
// Staging (rule #21, both-sides): per 8-row glds16 call the row-bit-4 is call-constant
// ((r0>>4)&1) -> XOR folded into the pre-swizzled global source, zero inner-loop cost.
// Everything else byte-identical to R5 (absmax 0.0-proven mapping and tail).

__launch_bounds__(256, 2)
__global__ void argmin_mfma_kernel(const u16* __restrict__ A,   // [32768][256]
                                   const u16* __restrict__ eT,  // [8192][256]
                                   const float* __restrict__ e2f,
                                   int* __restrict__ keys) {    // [3][2][NP]
    __shared__ u16 Ast[4][PXT * 64];  // 64 KB resident A, XOR-swizzled slots
    __shared__ u16 Bst[NTT * 64];     // 16 KB streamed B

    const int t = threadIdx.x;
    const int w = t >> 6;        // wave 0..3
    const int l = t & 63;
    const int wm = w & 1;        // M-group: rows wm*64 .. +64
    const int wn = w >> 1;       // N-group: cols wn*64 .. +64
    const int split = blockIdx.x & 1;
    const int pxt   = blockIdx.x >> 1;
    const int px0 = pxt * PXT;
    const int kb0 = split * KSPLIT;

    const int swz  = (l & 7) ^ ((l >> 3) & 7);
    const int srow = l >> 3;
    const int c32  = l & 31;     // A-row / B-col / C-col lane index
    const int h    = l >> 5;     // k-half selector & C-row offset
    const int slx  = l & 7;      // (row&7) for fragment reads
    const int xr   = ((l >> 4) & 1) << 2;   // row-bit-4 swizzle term (fragment reads)

    // ---- A prologue stage: rows w*32..+32, 4 kits; source pre-XORed with row-bit-4 ----
#pragma unroll
    for (int c = 0; c < 4; ++c)
#pragma unroll
        for (int i = 0; i < 4; ++i) {
            int r0 = w * 32 + i * 8;
            int xb = ((r0 >> 4) & 1) << 2;          // call-constant row-bit-4
            const u16* gp = A + (size_t)(px0 + r0 + srow) * 256 + c * 64 + (swz ^ xb) * 8;
            glds16(gp, &Ast[c][r0 * 64]);
        }

    int b1[32], b2[32];
#pragma unroll
    for (int i = 0; i < 32; ++i) { b1[i] = 0x7FFFFFFF; b2[i] = 0x7FFFFFFF; }

    for (int nt = 0; nt < KSPLIT / NTT; ++nt) {
        const int n0 = kb0 + nt * NTT;
        f32x16 acc[2][2];
#pragma unroll
        for (int ti = 0; ti < 2; ++ti)
#pragma unroll
            for (int tj = 0; tj < 2; ++tj)
#pragma unroll
                for (int r = 0; r < 16; ++r) acc[ti][tj][r] = 0.f;

        for (int kit = 0; kit < 4; ++kit) {
            __syncthreads();
#pragma unroll
            for (int i = 0; i < 4; ++i) {
                int r0 = w * 32 + i * 8;
                int xb = ((r0 >> 4) & 1) << 2;
                const u16* gp = eT + (size_t)(n0 + r0 + srow) * 256 + kit * 64 + (swz ^ xb) * 8;
                glds16(gp, &Bst[r0 * 64]);
            }
            __syncthreads();
#pragma unroll
            for (int sl = 0; sl < 4; ++sl) {         // k-slice of 16 within the kit's 64
                const int chunk = sl * 2 + h;        // logical 8-elem k-chunk 0..7
                const int slt = ((chunk ^ slx) ^ xr) * 8;
                bf16x8 af[2], bfr[2];
#pragma unroll
                for (int ti = 0; ti < 2; ++ti) {
                    int row = wm * 64 + ti * 32 + c32;
                    af[ti] = *(const bf16x8*)&Ast[kit][row * 64 + slt];
                }
#pragma unroll
                for (int tj = 0; tj < 2; ++tj) {
                    int row = wn * 64 + tj * 32 + c32;
                    bfr[tj] = *(const bf16x8*)&Bst[row * 64 + slt];
                }
#pragma unroll
                for (int ti = 0; ti < 2; ++ti)
#pragma unroll
                    for (int tj = 0; tj < 2; ++tj)
                        acc[ti][tj] = __builtin_amdgcn_mfma_f32_32x32x16_bf16(
                            af[ti], bfr[tj], acc[ti][tj], 0, 0, 0);
            }
        }

        // fold this nt's distances into per-row running top-2 keys
        float e2c[2];
        int   kcc[2];
#pragma unroll
        for (int tj = 0; tj < 2; ++tj) {
            kcc[tj] = n0 + wn * 64 + tj * 32 + c32;
            e2c[tj] = e2f[kcc[tj]] * 256.f;
        }
#pragma unroll
        for (int ti = 0; ti < 2; ++ti)
#pragma unroll
            for (int reg = 0; reg < 16; ++reg) {
                float d0 = fmaf(acc[ti][0][reg], -512.f, e2c[0]);
                float d1 = fmaf(acc[ti][1][reg], -512.f, e2c[1]);
                int ky0 = (int)d0 * 8192 + kcc[0];
                int ky1 = (int)d1 * 8192 + kcc[1];
                int kmin = min(ky0, ky1);
                int s = ti * 16 + reg;
                int v1 = min(b1[s], kmin);
                int x  = max(b1[s], kmin);
                b2[s] = min(b2[s], x);
                b1[s] = v1;
            }
    }

    // ---- per-slot 32-lane top-3 tree, then cross-wn merge via LDS (R5-proven tail) ----
    __syncthreads();               // all waves done reading Bst before overlay
    int* mrg = (int*)&Bst[0];      // 2*128*3 ints = 3 KB, Bst is dead now
#pragma unroll
    for (int s = 0; s < 32; ++s) {
        int c1 = b1[s], c2 = b2[s], c3 = 0x7FFFFFFF;
#pragma unroll
        for (int m = 1; m < 32; m <<= 1) {           // reduce within 32-lane halves
            int a1 = __shfl_xor(c1, m, 64);
            int a2 = __shfl_xor(c2, m, 64);
            int a3 = __shfl_xor(c3, m, 64);
            int m1 = min(c1, a1);
            int xx = max(c1, a1);
            int mn2 = min(c2, a2);
            int m2 = min(xx, mn2);
            int m3 = min(min(max(c2, a2), max(xx, mn2)), min(c3, a3));
            c1 = m1; c2 = m2; c3 = m3;
        }
        if (c32 == 0) {                               // lanes 0 and 32 (different rows)
            int ti = s >> 4, reg = s & 15;
            int row = wm * 64 + ti * 32 + (reg & 3) + 8 * (reg >> 2) + 4 * h;
            int o = (wn * 128 + row) * 3;
            mrg[o] = c1; mrg[o + 1] = c2; mrg[o + 2] = c3;
        }
    }
    __syncthreads();
    if (t < 128) {
        int a1 = mrg[t * 3], a2 = mrg[t * 3 + 1], a3 = mrg[t * 3 + 2];
        int u1 = mrg[(128 + t) * 3], u2 = mrg[(128 + t) * 3 + 1], u3 = mrg[(128 + t) * 3 + 2];
        int x1 = min(a1, u1), y1 = max(a1, u1);
        int n2 = min(a2, u2), M2 = max(a2, u2);
        int c1 = x1;
        int c2 = min(y1, n2);
        int c3 = min(max(y1, n2), min(M2, min(a3, u3)));
        int row = px0 + t;
        keys[split * NP + row]       = c1;
        keys[(2 + split) * NP + row] = c2;
        keys[(4 + split) * NP + row] = c3;
    }
}

// -------- finalize (fast-ws): dots + select + gather + out + loss, one pass (unchanged) --------
__global__ void finalize_kernel(const int* __restrict__ keys,
                                const float* __restrict__ z,
                                const float* __restrict__ eTf,
                                const float* __restrict__ e2f,
                                float* __restrict__ out,
                                float* __restrict__ loss) {
    __shared__ float smem[DD * 65];   // phase 1: zt[d*65+p]; phase 2: qt[p*257+d]
    __shared__ int   kc[384];
    __shared__ float dval[384];
    __shared__ int   kidx[64];
    const int t = threadIdx.x;
    const int n0 = blockIdx.x * 64;
    const float* zp = z + (size_t)(n0 >> 10) * (DD * HW) + (n0 & (HW - 1));

    for (int i = t; i < DD * 64; i += 256) {
        int d = i >> 6, p = i & 63;
        smem[d * 65 + p] = zp[(size_t)d * HW + p];   // coalesced
    }
    for (int i = t; i < 384; i += 256)
        kc[i] = keys[(i % 6) * NP + n0 + i / 6] & 8191;
    __syncthreads();

    const int l = t & 63, w = t >> 6;
    const int j = l & 15;   // lane within 16-lane dot group
    const int s = l >> 4;   // dot-group id within wave
#pragma unroll 2
    for (int it = 0; it < 24; ++it) {
        int dot = it * 16 + w * 4 + s;      // 0..383
        int p = dot / 6;
        int k = kc[dot];
        const float* er = eTf + (size_t)k * 256;
        float a = 0.f;
#pragma unroll
        for (int cc = 0; cc < 16; ++cc)
            a = fmaf(smem[(cc * 16 + j) * 65 + p], er[cc * 16 + j], a);
        a += __shfl_xor(a, 1, 64);
        a += __shfl_xor(a, 2, 64);
        a += __shfl_xor(a, 4, 64);
        a += __shfl_xor(a, 8, 64);
        if (j == 0) dval[dot] = fmaf(-2.f, a, e2f[k]);
    }
    __syncthreads();
    if (t < 64) {
        float bv = dval[t * 6];
        int   bk = kc[t * 6];
#pragma unroll
        for (int c = 1; c < 6; ++c) {
            float dv = dval[t * 6 + c];
            int   kk = kc[t * 6 + c];
            if (dv < bv || (dv == bv && kk < bk)) { bv = dv; bk = kk; }
        }
        kidx[t] = bk;
    }
    __syncthreads();

    // phase 2: bounce the 64 winning eTf rows through smem (zt is dead)
    float* qt = smem;                 // [p][d] pad 257 (257%32==1: conflict-free)
    for (int m = 0; m < 64; ++m)      // row m: 256 threads read the 1 KB row
        qt[m * 257 + t] = eTf[(size_t)kidx[m] * 256 + t];
    __syncthreads();

    const int p = t & 63, q = t >> 6;
    const size_t base = (size_t)(n0 >> 10) * (DD * HW) + (n0 & (HW - 1)) + p;
    float acc = 0.f;
#pragma unroll 8
    for (int i = 0; i < 64; ++i) {
        int d = q * 64 + i;
        float ev = qt[p * 257 + d];
        float zv = z[base + (size_t)d * HW];   // coalesced, L2-hot re-read
        out[base + (size_t)d * HW] = zv + (ev - zv);
        float df = ev - zv;
        acc = fmaf(df, df, acc);
    }
#pragma unroll
    for (int off = 32; off > 0; off >>= 1) acc += __shfl_down(acc, off, 64);
    __shared__ float part[4];
    if ((t & 63) == 0) part[t >> 6] = acc;
    __syncthreads();
    if (t == 0) {
        float s2 = (part[0] + part[1] + part[2] + part[3]) * (1.25f / 8388608.f);
        atomicAdd(loss, s2);
    }
}

// -------- slow-ws path: proven separate combine + gather (unchanged) --------
__global__ void combine_kernel(const int* __restrict__ keys,
                               const float* __restrict__ z,
                               const float* __restrict__ eTf,
                               const float* __restrict__ e2f,
                               int* __restrict__ idx) {
    __shared__ float zt[DD * 65];
    __shared__ int   kc[384];
    __shared__ float dval[384];
    const int t = threadIdx.x;
    const int n0 = blockIdx.x * 64;
    const float* zp = z + (size_t)(n0 >> 10) * (DD * HW) + (n0 & (HW - 1));
    for (int i = t; i < DD * 64; i += 256) {
        int d = i >> 6, p = i & 63;
        zt[d * 65 + p] = zp[(size_t)d * HW + p];
    }
    for (int i = t; i < 384; i += 256)
        kc[i] = keys[(i % 6) * NP + n0 + i / 6] & 8191;
    __syncthreads();

    const int l = t & 63, w = t >> 6;
    const int j = l & 15;
    const int s = l >> 4;
#pragma unroll 2
    for (int it = 0; it < 24; ++it) {
        int dot = it * 16 + w * 4 + s;
        int p = dot / 6;
        int k = kc[dot];
        const float* er = eTf + (size_t)k * 256;
        float a = 0.f;
#pragma unroll
        for (int cc = 0; cc < 16; ++cc)
            a = fmaf(zt[(cc * 16 + j) * 65 + p], er[cc * 16 + j], a);
        a += __shfl_xor(a, 1, 64);
        a += __shfl_xor(a, 2, 64);
        a += __shfl_xor(a, 4, 64);
        a += __shfl_xor(a, 8, 64);
        if (j == 0) dval[dot] = fmaf(-2.f, a, e2f[k]);
    }
    __syncthreads();
    if (t < 64) {
        float bv = dval[t * 6];
        int   bk = kc[t * 6];
#pragma unroll
        for (int c = 1; c < 6; ++c) {
            float dv = dval[t * 6 + c];
            int   kk = kc[t * 6 + c];
            if (dv < bv || (dv == bv && kk < bk)) { bv = dv; bk = kk; }
        }
        idx[n0 + t] = bk;
    }
}

__global__ void gather_slow_kernel(const float* __restrict__ z,
                                   const float* __restrict__ e,
                                   const int* __restrict__ idx,
                                   float* __restrict__ out,
                                   float* __restrict__ loss) {
    const int t = threadIdx.x;
    const int n0 = blockIdx.x * 64;
    __shared__ int kidx[64];
    if (t < 64) kidx[t] = idx[n0 + t];
    __syncthreads();

    const int p = t & 63;
    const int d0 = t >> 6;
    const size_t base = (size_t)(n0 >> 10) * (DD * HW) + (n0 & (HW - 1)) + p;
    const int kk = kidx[p];

    float acc = 0.f;
    for (int d = d0; d < DD; d += 4) {
        float ev = e[(size_t)d * KN + kk];
        float zv = z[base + (size_t)d * HW];
        out[base + (size_t)d * HW] = zv + (ev - zv);
        float df = ev - zv;
        acc = fmaf(df, df, acc);
    }
#pragma unroll
    for (int off = 32; off > 0; off >>= 1) acc += __shfl_down(acc, off, 64);
    __shared__ float part[4];
    if ((t & 63) == 0) part[t >> 6] = acc;
    __syncthreads();
    if (t == 0) {
        float s = (part[0] + part[1] + part[2] + part[3]) * (1.25f / 8388608.f);
        atomicAdd(loss, s);
    }
}

extern "C" void kernel_launch(void* const* d_in, const int* in_sizes, int n_in,
                              void* d_out, int out_size, void* d_ws, size_t ws_size,
                              hipStream_t stream) {
    const float* z = (const float*)d_in[0];   // [32,256,32,32] fp32
    const float* e = (const float*)d_in[1];   // [256,8192] fp32
    float* out = (float*)d_out;
    float* loss = out + (size_t)NP * DD;      // element 8388608

    char* ob = (char*)d_out;
    char* ws = (char*)d_ws;
    u16* Acat = (u16*)ob;                            // [0, 16Mi) — consumed by argmin
    u16* eT   = (u16*)(ob + ((size_t)16 << 20));     // [16Mi, 20Mi) — consumed by argmin

    float* e2f = (float*)ws;                         // 32 KB (proven-safe region)
    int*   idx = (int*)(ws + (32 << 10));            // 128 KB
    int*   keys;
    float* eTf;
    const bool fastws = ws_size >= ((size_t)10 << 20);
    if (fastws) {
        keys = (int*)(ws + (160 << 10));             // 768 KB @ 160K
        eTf  = (float*)(ws + ((size_t)1 << 20));     // 8 MB @ 1M
    } else {
        keys = (int*)(ob + ((size_t)20 << 20));      // d_out scratch (R6-proven)
        eTf  = (float*)(ob + ((size_t)23 << 20));
    }

    prep_kernel<<<2592, 256, 0, stream>>>(e, z, eT, eTf, e2f, Acat);
    argmin_mfma_kernel<<<SPLITS * (NP / PXT), 256, 0, stream>>>(Acat, eT, e2f, keys);
    hipMemsetAsync(loss, 0, sizeof(float), stream);
    if (fastws) {
        finalize_kernel<<<NP / 64, 256, 0, stream>>>(keys, z, eTf, e2f, out, loss);
    } else {
        combine_kernel<<<NP / 64, 256, 0, stream>>>(keys, z, eTf, e2f, idx);
        gather_slow_kernel<<<NP / 64, 256, 0, stream>>>(z, e, idx, out, loss);
    }
}